// Round 10
// baseline (216.978 us; speedup 1.0000x reference)
//
#include <hip/hip_runtime.h>
#include <hip/hip_bf16.h>
#include <cstdint>

#define BB 16
#define LL 32768
#define NC 512               // chunks per (b,dir)

// ---- weight block layout (floats) in ws[0..4096B) ----
#define WD_SZ 256
#define XPW 0                // x_proj rows [33][4]
#define CVW 132
#define CVB 148
#define DTW 152
#define DTB 156
#define AW  160              // A2 = -exp(A_log)*log2e [4][16]
#define DW  224
#define G_INPROJ 512
#define G_NORMW 528
#define G_OUTP 530
#define G_NORMF 538
#define FLG 1000             // 1.0f if fp32 I/O, 0.0f if bf16

// ---- ws layout (~12.8 MB) ----
#define PQ_OFF 4096
#define PQ_BYTES ((size_t)BB*2*NC*64*8)
#define HIN_OFF (PQ_OFF + PQ_BYTES)
#define HIN_BYTES ((size_t)BB*2*NC*64*4)
#define SEG_OFF (HIN_OFF + HIN_BYTES)
#define SEG_BYTES ((size_t)BB*2*8*64*8)
#define SEGI_OFF (SEG_OFF + SEG_BYTES)

__device__ __forceinline__ float bf2f(unsigned short u){ return __uint_as_float(((unsigned int)u)<<16); }
__device__ __forceinline__ float blo(unsigned int u){ return __uint_as_float(u<<16); }
__device__ __forceinline__ float bhi(unsigned int u){ return __uint_as_float(u & 0xffff0000u); }
__device__ __forceinline__ unsigned short f2bf(float f){
  unsigned int x = __float_as_uint(f);
  x += 0x7fffu + ((x>>16)&1u);
  return (unsigned short)(x>>16);
}
__device__ __forceinline__ unsigned int pack2(float a, float b){
  __hip_bfloat162 h = __float22bfloat162_rn(make_float2(a,b));
  union { __hip_bfloat162 h2; unsigned int u; } cv; cv.h2 = h;
  return cv.u;
}
__device__ __forceinline__ float siluf(float x){
  return x * __builtin_amdgcn_rcpf(1.f + __expf(-x));
}
__device__ __forceinline__ float softplusf_(float x){
  return fmaxf(x,0.f) + 0.69314718056f*__log2f(1.f + __expf(-fabsf(x)));
}
// butterfly sum over the 16-lane row (n=0..15 within each d-group)
__device__ __forceinline__ float rowsum16(float x){
  union { float f; int i; } a, t;
  a.f = x;
  t.i = __builtin_amdgcn_update_dpp(0, a.i, 0x121, 0xf, 0xf, true); a.f += t.f;
  t.i = __builtin_amdgcn_update_dpp(0, a.i, 0x122, 0xf, 0xf, true); a.f += t.f;
  t.i = __builtin_amdgcn_update_dpp(0, a.i, 0x124, 0xf, 0xf, true); a.f += t.f;
  t.i = __builtin_amdgcn_update_dpp(0, a.i, 0x128, 0xf, 0xf, true); a.f += t.f;
  return a.f;
}
__device__ __forceinline__ float ldw(const void* p, int i, int isf){
  return isf ? ((const float*)p)[i] : bf2f(((const unsigned short*)p)[i]);
}
__device__ __forceinline__ float2 hid2(const void* hid, int isf, int b, int t){
  if (isf){
    const float* p = (const float*)hid;
    return make_float2(p[(size_t)b*2*LL + t], p[(size_t)b*2*LL + LL + t]);
  }
  const unsigned short* p = (const unsigned short*)hid;
  return make_float2(bf2f(p[(size_t)b*2*LL + t]), bf2f(p[(size_t)b*2*LL + LL + t]));
}
__device__ __forceinline__ float4 xrow(const void* __restrict__ hid, int isf,
                                       const float* __restrict__ W, int b, int t){
  float2 h = hid2(hid, isf, b, t);
  float ms = rsqrtf(0.5f*(h.x*h.x + h.y*h.y) + 1e-5f);
  float v0 = h.x*ms*W[G_NORMW], v1 = h.y*ms*W[G_NORMW+1];
  float4 x;
  x.x = W[G_INPROJ+0]*v0 + W[G_INPROJ+1]*v1;
  x.y = W[G_INPROJ+2]*v0 + W[G_INPROJ+3]*v1;
  x.z = W[G_INPROJ+4]*v0 + W[G_INPROJ+5]*v1;
  x.w = W[G_INPROJ+6]*v0 + W[G_INPROJ+7]*v1;
  return x;
}

// conv+silu for direction dr at local position `lane` given x tile
__device__ __forceinline__ void convu(const float4* xb, int lane, const float* Wd, int dr, float* u){
  if (dr == 0){
    float4 xk0=xb[lane],xk1=xb[lane+1],xk2=xb[lane+2],xk3=xb[lane+3];
    u[0] = siluf(Wd[CVB+0] + Wd[CVW+ 0]*xk0.x + Wd[CVW+ 1]*xk1.x + Wd[CVW+ 2]*xk2.x + Wd[CVW+ 3]*xk3.x);
    u[1] = siluf(Wd[CVB+1] + Wd[CVW+ 4]*xk0.y + Wd[CVW+ 5]*xk1.y + Wd[CVW+ 6]*xk2.y + Wd[CVW+ 7]*xk3.y);
    u[2] = siluf(Wd[CVB+2] + Wd[CVW+ 8]*xk0.z + Wd[CVW+ 9]*xk1.z + Wd[CVW+10]*xk2.z + Wd[CVW+11]*xk3.z);
    u[3] = siluf(Wd[CVB+3] + Wd[CVW+12]*xk0.w + Wd[CVW+13]*xk1.w + Wd[CVW+14]*xk2.w + Wd[CVW+15]*xk3.w);
  } else {
    float4 xk3=xb[lane+3],xk4=xb[lane+4],xk5=xb[lane+5],xk6=xb[lane+6];
    u[0] = siluf(Wd[CVB+0] + Wd[CVW+ 0]*xk6.x + Wd[CVW+ 1]*xk5.x + Wd[CVW+ 2]*xk4.x + Wd[CVW+ 3]*xk3.x);
    u[1] = siluf(Wd[CVB+1] + Wd[CVW+ 4]*xk6.y + Wd[CVW+ 5]*xk5.y + Wd[CVW+ 6]*xk4.y + Wd[CVW+ 7]*xk3.y);
    u[2] = siluf(Wd[CVB+2] + Wd[CVW+ 8]*xk6.z + Wd[CVW+ 9]*xk5.z + Wd[CVW+10]*xk4.z + Wd[CVW+11]*xk3.z);
    u[3] = siluf(Wd[CVB+3] + Wd[CVW+12]*xk6.w + Wd[CVW+13]*xk5.w + Wd[CVW+14]*xk4.w + Wd[CVW+15]*xk3.w);
  }
}

// ---------------- kernel 0: weight prep + dtype detect ----------------
__global__ void k_prep(const void* __restrict__ normw, const void* __restrict__ inpj,
    const void* __restrict__ cwf, const void* __restrict__ cbf,
    const void* __restrict__ xpf, const void* __restrict__ dwf,
    const void* __restrict__ dbf, const void* __restrict__ alf,
    const void* __restrict__ ddf,
    const void* __restrict__ cwb, const void* __restrict__ cbb,
    const void* __restrict__ xpb, const void* __restrict__ dwb,
    const void* __restrict__ dbb, const void* __restrict__ alb,
    const void* __restrict__ ddb,
    const void* __restrict__ outp, const void* __restrict__ nfw,
    float* __restrict__ W)
{
  const int isf = (((const unsigned int*)ddf)[0] == 0x3F800000u) ? 1 : 0;
  int t = threadIdx.x;
  for (int i=t;i<132;i+=256){ W[XPW+i]=ldw(xpf,i,isf); W[WD_SZ+XPW+i]=ldw(xpb,i,isf); }
  for (int i=t;i<16;i+=256){ W[CVW+i]=ldw(cwf,i,isf); W[WD_SZ+CVW+i]=ldw(cwb,i,isf); W[G_INPROJ+i]=ldw(inpj,i,isf); }
  for (int i=t;i<4;i+=256){
    W[CVB+i]=ldw(cbf,i,isf); W[WD_SZ+CVB+i]=ldw(cbb,i,isf);
    W[DTW+i]=ldw(dwf,i,isf); W[WD_SZ+DTW+i]=ldw(dwb,i,isf);
    W[DTB+i]=ldw(dbf,i,isf); W[WD_SZ+DTB+i]=ldw(dbb,i,isf);
    W[DW+i] =ldw(ddf,i,isf); W[WD_SZ+DW+i] =ldw(ddb,i,isf);
  }
  for (int i=t;i<64;i+=256){
    W[AW+i]       = -__expf(ldw(alf,i,isf)) * 1.44269504089f;
    W[WD_SZ+AW+i] = -__expf(ldw(alb,i,isf)) * 1.44269504089f;
  }
  for (int i=t;i<8;i+=256) W[G_OUTP+i]=ldw(outp,i,isf);
  for (int i=t;i<2;i+=256){ W[G_NORMW+i]=ldw(normw,i,isf); W[G_NORMF+i]=ldw(nfw,i,isf); }
  if (t==0) W[FLG] = (float)isf;
}

// ---------------- kernel 1: per-chunk (P,Q); 1 chunk/block, wave=dir ----------------
__global__ __launch_bounds__(128) void k_chunk(const void* __restrict__ hid,
    const float* __restrict__ W, float2* __restrict__ PQ)
{
  __shared__ __align__(16) float4 xb[70];
  __shared__ __align__(16) unsigned int   DU[2][4*68];   // dt|dt*u bf16
  __shared__ __align__(16) unsigned short Bs[2][16*72];  // B bf16
  const int lane = threadIdx.x & 63;
  const int w    = threadIdx.x >> 6;       // = direction
  const int gid  = blockIdx.x;             // (b,c)
  const int c    = gid & (NC-1);
  const int b    = gid >> 9;
  const int isf  = (int)W[FLG];

  // Phase A1: x tile (wave0 main, wave1 halos)
  if (w == 0){
    xb[lane+3] = xrow(hid, isf, W, b, c*64 + lane);
  } else {
    if (lane < 3){
      int t2 = c*64 - 3 + lane;
      float4 v = make_float4(0.f,0.f,0.f,0.f);
      if (t2 >= 0) v = xrow(hid, isf, W, b, t2);
      xb[lane] = v;
    }
    if (lane >= 61){
      int t3 = c*64 + lane + 3;
      float4 v = make_float4(0.f,0.f,0.f,0.f);
      if (t3 < LL) v = xrow(hid, isf, W, b, t3);
      xb[lane+6] = v;
    }
  }
  __syncthreads();
  // Phase A2: per-dir projections (wave w handles dir w only)
  const float* Wd = W + w*WD_SZ;
  {
    float u[4];
    convu(xb, lane, Wd, w, u);
    float dtr = Wd[XPW+0]*u[0]+Wd[XPW+1]*u[1]+Wd[XPW+2]*u[2]+Wd[XPW+3]*u[3];
    #pragma unroll
    for (int d2=0; d2<4; d2++){
      float dt = softplusf_(fmaf(Wd[DTW+d2], dtr, Wd[DTB+d2]));
      DU[w][d2*68+lane] = pack2(dt, dt*u[d2]);
    }
    #pragma unroll
    for (int n=0;n<16;n++){
      float Bn = Wd[XPW+(1+n)*4+0]*u[0]+Wd[XPW+(1+n)*4+1]*u[1]
               + Wd[XPW+(1+n)*4+2]*u[2]+Wd[XPW+(1+n)*4+3]*u[3];
      Bs[w][n*72+lane] = f2bf(Bn);
    }
  }
  // no barrier: wave w reads only planes [w] it wrote
  const int d = lane>>4, n = lane&15;
  const float A2 = Wd[AW + d*16 + n];
  float P=1.f, Q=0.f;
  for (int j4=0; j4<16; j4++){
    const int t0 = w ? (60 - j4*4) : (j4*4);
    uint4 u4 = *(const uint4*)&DU[w][d*68+t0];
    ushort4 b4 = *(const ushort4*)&Bs[w][n*72+t0];
    unsigned int ua[4]={u4.x,u4.y,u4.z,u4.w};
    unsigned short ba[4]={b4.x,b4.y,b4.z,b4.w};
    #pragma unroll
    for (int jr=0; jr<4; jr++){
      const int k = w ? (3-jr) : jr;      // bwd consumes t descending
      float e = exp2f(A2*blo(ua[k]));
      P *= e;
      Q = fmaf(Q, e, bhi(ua[k])*bf2f(ba[k]));
    }
  }
  const int cs = w ? (NC-1-c) : c;        // position in this dir's sequence
  PQ[((size_t)(b*2+w)*NC + cs)*64 + lane] = make_float2(P,Q);
}

// ---------------- kernel 2a: segment reduce (bd x 8 segs of 64 chunks) ----------------
__global__ __launch_bounds__(64) void k_scan1(const float2* __restrict__ PQ, float2* __restrict__ SEG)
{
  const int blk = blockIdx.x;        // bd*8 + s
  const int bd = blk>>3, s = blk&7;
  const int lane = threadIdx.x;
  const size_t base = (size_t)bd*NC + s*64;
  float R=1.f, H=0.f;
  for (int cc=0; cc<64; cc+=16){
    float2 v[16];
    #pragma unroll
    for (int k=0;k<16;k++) v[k] = PQ[(base+cc+k)*64+lane];
    #pragma unroll
    for (int k=0;k<16;k++){ H = fmaf(v[k].x, H, v[k].y); R *= v[k].x; }
  }
  SEG[(size_t)blk*64+lane] = make_float2(R,H);
}

// ---------------- kernel 2b: scan 8 segments per bd ----------------
__global__ __launch_bounds__(64) void k_scan2(const float2* __restrict__ SEG, float* __restrict__ SEGI)
{
  const int bd = blockIdx.x;
  const int lane = threadIdx.x;
  float h = 0.f;
  #pragma unroll
  for (int s=0;s<8;s++){
    SEGI[((size_t)bd*8+s)*64+lane] = h;
    float2 rh = SEG[((size_t)bd*8+s)*64+lane];
    h = fmaf(rh.x, h, rh.y);
  }
}

// ---------------- kernel 2c: replay segments -> per-chunk initial h ----------------
__global__ __launch_bounds__(64) void k_scan3(const float2* __restrict__ PQ,
    const float* __restrict__ SEGI, float* __restrict__ hin)
{
  const int blk = blockIdx.x;        // bd*8 + s
  const int bd = blk>>3, s = blk&7;
  const int lane = threadIdx.x;
  const size_t base = (size_t)bd*NC + s*64;
  float h = SEGI[(size_t)blk*64+lane];
  for (int cc=0; cc<64; cc+=16){
    float2 v[16];
    #pragma unroll
    for (int k=0;k<16;k++) v[k] = PQ[(base+cc+k)*64+lane];
    #pragma unroll
    for (int k=0;k<16;k++){
      hin[(base+cc+k)*64+lane] = h;
      h = fmaf(v[k].x, h, v[k].y);
    }
  }
}

// ---------------- kernel 3: fused replay; 1 chunk/block, wave=dir ----------------
__global__ __launch_bounds__(128) void k_fused(const void* __restrict__ hid,
    const float* __restrict__ W, const float* __restrict__ hin,
    void* __restrict__ out)
{
  __shared__ __align__(16) float4 xb[70];
  __shared__ __align__(16) unsigned int DU[2][4*68];   // dt|dt*u
  __shared__ __align__(16) unsigned int BC[2][16*68];  // B|C
  __shared__ __align__(16) float zs[256];              // silu(z)
  __shared__ __align__(16) float uD[2][256];           // u*D per dir
  __shared__ __align__(16) float yS[2][4*68];          // y partial per dir
  const int lane = threadIdx.x & 63;
  const int w    = threadIdx.x >> 6;       // = direction
  const int gid  = blockIdx.x;             // (b,c)
  const int c    = gid & (NC-1);
  const int b    = gid >> 9;
  const int isf  = (int)W[FLG];

  const int cs = w ? (NC-1-c) : c;
  float hS = hin[((size_t)(b*2+w)*NC + cs)*64 + lane];

  // Phase A1
  if (w == 0){
    int t = c*64 + lane;
    float2 h = hid2(hid, isf, b, t);
    float ms = rsqrtf(0.5f*(h.x*h.x + h.y*h.y) + 1e-5f);
    float v0 = h.x*ms*W[G_NORMW], v1 = h.y*ms*W[G_NORMW+1];
    float4 x;
    x.x = W[G_INPROJ+0]*v0 + W[G_INPROJ+1]*v1;
    x.y = W[G_INPROJ+2]*v0 + W[G_INPROJ+3]*v1;
    x.z = W[G_INPROJ+4]*v0 + W[G_INPROJ+5]*v1;
    x.w = W[G_INPROJ+6]*v0 + W[G_INPROJ+7]*v1;
    xb[lane+3] = x;
    float4 z4;
    z4.x = siluf(W[G_INPROJ+ 8]*v0 + W[G_INPROJ+ 9]*v1);
    z4.y = siluf(W[G_INPROJ+10]*v0 + W[G_INPROJ+11]*v1);
    z4.z = siluf(W[G_INPROJ+12]*v0 + W[G_INPROJ+13]*v1);
    z4.w = siluf(W[G_INPROJ+14]*v0 + W[G_INPROJ+15]*v1);
    *(float4*)&zs[lane*4] = z4;
  } else {
    if (lane < 3){
      int t2 = c*64 - 3 + lane;
      float4 v = make_float4(0.f,0.f,0.f,0.f);
      if (t2 >= 0) v = xrow(hid, isf, W, b, t2);
      xb[lane] = v;
    }
    if (lane >= 61){
      int t3 = c*64 + lane + 3;
      float4 v = make_float4(0.f,0.f,0.f,0.f);
      if (t3 < LL) v = xrow(hid, isf, W, b, t3);
      xb[lane+6] = v;
    }
  }
  __syncthreads();
  // Phase A2 per dir
  const float* Wd = W + w*WD_SZ;
  {
    float u[4];
    convu(xb, lane, Wd, w, u);
    *(float4*)&uD[w][lane*4] = make_float4(u[0]*Wd[DW+0], u[1]*Wd[DW+1], u[2]*Wd[DW+2], u[3]*Wd[DW+3]);
    float dtr = Wd[XPW+0]*u[0]+Wd[XPW+1]*u[1]+Wd[XPW+2]*u[2]+Wd[XPW+3]*u[3];
    #pragma unroll
    for (int d2=0; d2<4; d2++){
      float dt = softplusf_(fmaf(Wd[DTW+d2], dtr, Wd[DTB+d2]));
      DU[w][d2*68+lane] = pack2(dt, dt*u[d2]);
    }
    #pragma unroll
    for (int n=0;n<16;n++){
      float Bn = Wd[XPW+(1+n)*4+0]*u[0]+Wd[XPW+(1+n)*4+1]*u[1]
               + Wd[XPW+(1+n)*4+2]*u[2]+Wd[XPW+(1+n)*4+3]*u[3];
      float Cn = Wd[XPW+(17+n)*4+0]*u[0]+Wd[XPW+(17+n)*4+1]*u[1]
               + Wd[XPW+(17+n)*4+2]*u[2]+Wd[XPW+(17+n)*4+3]*u[3];
      BC[w][n*68+lane] = pack2(Bn,Cn);
    }
  }
  // Phase B (own planes; no barrier needed before this)
  {
    const int d = lane>>4, n = lane&15;
    const float A2 = Wd[AW + d*16 + n];
    for (int j4=0; j4<16; j4++){
      const int t0 = w ? (60 - j4*4) : (j4*4);
      uint4 u4 = *(const uint4*)&DU[w][d*68+t0];
      uint4 c4 = *(const uint4*)&BC[w][n*68+t0];
      unsigned int ua[4]={u4.x,u4.y,u4.z,u4.w};
      unsigned int ca[4]={c4.x,c4.y,c4.z,c4.w};
      float s[4];
      #pragma unroll
      for (int jr=0; jr<4; jr++){
        const int k = w ? (3-jr) : jr;
        float e = exp2f(A2*blo(ua[k]));
        hS = fmaf(e, hS, bhi(ua[k])*blo(ca[k]));
        s[k] = rowsum16(hS*bhi(ca[k]));
      }
      if (n == 0) *(float4*)&yS[w][d*68+t0] = make_float4(s[0],s[1],s[2],s[3]);
    }
  }
  __syncthreads();
  // Phase C (wave0 only)
  if (w == 0){
    int t = c*64 + lane;
    float4 zz = *(const float4*)&zs[lane*4];
    float4 u0 = *(const float4*)&uD[0][lane*4];
    float4 u1 = *(const float4*)&uD[1][lane*4];
    float y0 = (yS[0][0*68+lane] + yS[1][0*68+lane] + u0.x + u1.x) * zz.x;
    float y1 = (yS[0][1*68+lane] + yS[1][1*68+lane] + u0.y + u1.y) * zz.y;
    float y2 = (yS[0][2*68+lane] + yS[1][2*68+lane] + u0.z + u1.z) * zz.z;
    float y3 = (yS[0][3*68+lane] + yS[1][3*68+lane] + u0.w + u1.w) * zz.w;
    float o0 = W[G_OUTP+0]*y0 + W[G_OUTP+1]*y1 + W[G_OUTP+2]*y2 + W[G_OUTP+3]*y3;
    float o1 = W[G_OUTP+4]*y0 + W[G_OUTP+5]*y1 + W[G_OUTP+6]*y2 + W[G_OUTP+7]*y3;
    float2 r = hid2(hid, isf, b, t);
    o0 += r.x;
    o1 += r.y;
    float ms = rsqrtf(0.5f*(o0*o0 + o1*o1) + 1e-5f);
    float e0 = o0*ms*W[G_NORMF], e1 = o1*ms*W[G_NORMF+1];
    size_t i0 = (size_t)b*2*LL + t, i1 = i0 + LL;
    if (isf){
      ((float*)out)[i0] = e0;
      ((float*)out)[i1] = e1;
    } else {
      ((unsigned short*)out)[i0] = f2bf(e0);
      ((unsigned short*)out)[i1] = f2bf(e1);
    }
  }
}

extern "C" void kernel_launch(void* const* d_in, const int* in_sizes, int n_in,
                              void* d_out, int out_size, void* d_ws, size_t ws_size,
                              hipStream_t stream)
{
  (void)in_sizes; (void)n_in; (void)out_size; (void)ws_size;
  const void* hid = d_in[0];
  float* W     = (float*)d_ws;
  float2* PQ   = (float2*)((char*)d_ws + PQ_OFF);
  float* hin   = (float*)((char*)d_ws + HIN_OFF);
  float2* SEG  = (float2*)((char*)d_ws + SEG_OFF);
  float* SEGI  = (float*)((char*)d_ws + SEGI_OFF);

  k_prep<<<1,256,0,stream>>>(d_in[1], d_in[2], d_in[3], d_in[4], d_in[5], d_in[6],
                             d_in[7], d_in[8], d_in[9], d_in[10], d_in[11], d_in[12],
                             d_in[13], d_in[14], d_in[15], d_in[16], d_in[17], d_in[18], W);
  k_chunk<<<BB*NC, 128, 0, stream>>>(hid, W, PQ);
  k_scan1<<<BB*2*8, 64, 0, stream>>>(PQ, SEG);
  k_scan2<<<BB*2, 64, 0, stream>>>(SEG, SEGI);
  k_scan3<<<BB*2*8, 64, 0, stream>>>(PQ, SEGI, hin);
  k_fused<<<BB*NC, 128, 0, stream>>>(hid, W, hin, d_out);
}